// Round 11
// baseline (224.730 us; speedup 1.0000x reference)
//
#include <hip/hip_runtime.h>
#include <hip/hip_fp16.h>

#define N_NODES 100000
#define N_EDGES 3200000
#define F_IN    128
#define F_HID   32

#define BSHIFT  7
#define BKSZ    128                               // nodes per bucket
#define NBKT    ((N_NODES + BKSZ - 1) / BKSZ)     // 782
#define CAP     5120                              // bucket capacity: mean 4092 + 8 sigma + 4-align pad
#define CHUNK   4096                              // edges per partition block
#define NBLK_E  ((N_EDGES + CHUNK - 1) / CHUNK)   // 782
#define RBITS   17                                // row id bits (100000 < 2^17)
#define RMASK   0x1FFFF

typedef _Float16 f16;
typedef f16   f16x8 __attribute__((ext_vector_type(8)));
typedef float f32x4 __attribute__((ext_vector_type(4)));
typedef int   i32x4 __attribute__((ext_vector_type(4)));
#define WPAD 136   // padded f16 row length: stride 272 B -> 68 dw = 4 mod 32 banks (2-way, free)

// fast tanh: 1 - 2/(exp2(x*2/ln2)+1). v_exp_f32 + v_rcp_f32 are ~1ulp approx
// -> abs err ~1e-6, far under the fp16-storage error budget (absmax ~1e-3).
__device__ __forceinline__ float fast_tanh(float x) {
    float t = __builtin_amdgcn_exp2f(x * 2.88539008f);   // e^{2x}
    return 1.0f - 2.0f * __builtin_amdgcn_rcpf(t + 1.0f);
}

// ---------------- coarse partition (fixed-capacity buckets, relative cursors) ----------------
// gcur[] zeroed by hipMemsetAsync; holds per-bucket edge count after k_part.
// R22: edge-list reads are non-temporal (stream-once; keep L2 for reused data).

__global__ __launch_bounds__(512) void k_part(const int* __restrict__ row, const int* __restrict__ col,
                                              int* __restrict__ gcur, unsigned* __restrict__ bkt) {
    __shared__ int hist[NBKT];
    __shared__ int lbase[NBKT];          // local (block) exclusive prefix
    __shared__ int gbase[NBKT];          // global destination base (absolute)
    __shared__ unsigned perm[CHUNK];     // 16 KB: packed words, bucket-major
    __shared__ unsigned short pb[CHUNK]; // 8 KB: bucket id per slot
    __shared__ int wt[8];
    int t = threadIdx.x;
    for (int i = t; i < NBKT; i += 512) hist[i] = 0;
    __syncthreads();

    int e0 = blockIdx.x * CHUNK;
    int n  = min(CHUNK, N_EDGES - e0);
    int r[8], c[8], rk[8];
#pragma unroll
    for (int k = 0; k < 8; k++) {
        int idx = t + k * 512;
        if (idx < n) {
            r[k]  = __builtin_nontemporal_load(row + e0 + idx);
            c[k]  = __builtin_nontemporal_load(col + e0 + idx);
            rk[k] = atomicAdd(&hist[c[k] >> BSHIFT], 1);   // local rank in bucket
        }
    }
    __syncthreads();

    // block scan: each thread owns 2 consecutive buckets
    {
        int b0 = t * 2;
        int s0 = (b0     < NBKT) ? hist[b0]     : 0;
        int s1 = (b0 + 1 < NBKT) ? hist[b0 + 1] : 0;
        int tsum = s0 + s1;
        int lane = t & 63, wid = t >> 6;
        int incl = tsum;
#pragma unroll
        for (int sh = 1; sh < 64; sh <<= 1) {
            int u = __shfl_up(incl, sh);
            if (lane >= sh) incl += u;
        }
        if (lane == 63) wt[wid] = incl;
        __syncthreads();
        int wpre = 0;
        for (int w = 0; w < wid; w++) wpre += wt[w];
        int excl = wpre + incl - tsum;
        if (b0     < NBKT) lbase[b0]     = excl;
        if (b0 + 1 < NBKT) lbase[b0 + 1] = excl + s0;
    }
    for (int i = t; i < NBKT; i += 512) {
        int h = hist[i];
        gbase[i] = i * CAP + (h ? atomicAdd(&gcur[i], h) : 0);
    }
    __syncthreads();

#pragma unroll
    for (int k = 0; k < 8; k++) {
        int idx = t + k * 512;
        if (idx < n) {
            int b   = c[k] >> BSHIFT;
            int pos = lbase[b] + rk[k];
            perm[pos] = (unsigned)r[k] | ((unsigned)(c[k] & (BKSZ - 1)) << RBITS);
            pb[pos]   = (unsigned short)b;
        }
    }
    __syncthreads();

    for (int i = t; i < n; i += 512) {
        int b = pb[i];
        bkt[gbase[b] + (i - lbase[b])] = perm[i];
    }
}

// ---------------- k_bucket R21: fine sort + FUSED MFMA gemm1 ----------------
// Phases 1-3 as R17 (stage to LDS, histogram, scan -> off/end(padded)/dinv, dinv also to
// LDS). Then the 16 waves split: waves 0-7 scatter srt (in place), waves 8-15 compute
// h1s = fp16(dinv*(x@W1)) for the block's 128 rows via 8 MFMA 16-row tiles.
// R22: bkt stage reads non-temporal (stream-once).

__global__ __launch_bounds__(1024) void k_bucket(unsigned* __restrict__ bkt,  // in: bkt, out: srt
                                                 const int* __restrict__ gcur,
                                                 int* __restrict__ off, int* __restrict__ end,
                                                 float* __restrict__ dinv,
                                                 const float* __restrict__ x,
                                                 const float* __restrict__ W1,
                                                 unsigned* __restrict__ h1s) {
    __shared__ unsigned stg[CAP];        // 20.5 KB staging
    __shared__ int cnt[BKSZ];            // histogram; aliased as cur after the scan
    __shared__ int wtot[2];
    __shared__ float dlds[BKSZ];         // dinv for this block's 128 nodes
    __shared__ f16 WH[F_HID * WPAD];     // 8.7 KB: W1 transposed [f][k], f16
    __shared__ f16 XH[8][16 * WPAD];     // 34.8 KB: per-MFMA-wave x tile [row][k], f16
    int t = threadIdx.x, b = blockIdx.x;
    int s = b * CAP, m = gcur[b];        // gcur holds the bucket count
    if (t < BKSZ) cnt[t] = 0;
    for (int i = t; i < F_IN * F_HID; i += 1024) {   // W1[k][f] f32 -> WH[f][k] f16
        int k = i >> 5, f = i & 31;
        WH[f * WPAD + k] = (f16)W1[i];
    }
    if (b == 0 && t < 8)                 // zero row N_NODES for pad-edge gathers
        ((uint2*)h1s)[(size_t)N_NODES * 8 + t] = make_uint2(0u, 0u);
    __syncthreads();
    for (int i = t; i < m; i += 1024) {
        unsigned xx = __builtin_nontemporal_load(bkt + s + i);
        stg[i] = xx;
        atomicAdd(&cnt[xx >> RBITS], 1);
    }
    __syncthreads();

    int lane = t & 63, wid = t >> 6;
    int v = 0, v4 = 0, incl = 0;
    if (t < BKSZ) {
        v  = cnt[t];
        v4 = (v + 3) & ~3;            // padded length
        incl = v4;
        #pragma unroll
        for (int sh = 1; sh < 64; sh <<= 1) {
            int u = __shfl_up(incl, sh);
            if (lane >= sh) incl += u;
        }
        if (lane == 63) wtot[wid] = incl;
    }
    __syncthreads();
    if (t < BKSZ) {
        int wpre = (wid == 1) ? wtot[0] : 0;
        int excl = wpre + incl - v4;
        int base = s + excl;          // 4-aligned
        cnt[t] = base;                // cnt reborn as cur (own-slot read above, safe)
        int g = b * BKSZ + t;
        float dv = rsqrtf((float)(v + 1));   // +1 self-loop (real degree)
        dlds[t] = dv;
        if (g < N_NODES) {
            off[g]  = base;
            end[g]  = base + v4;      // PADDED end
            dinv[g] = dv;
        }
        for (int j = v; j < v4; j++) bkt[base + j] = N_NODES;   // pad -> zero row id
    }
    __syncthreads();

    if (t < 512) {
        // ---- waves 0-7: fine-sort scatter (srt) ----
        for (int i = t; i < m; i += 512) {
            unsigned xx = stg[i];
            int p = atomicAdd(&cnt[xx >> RBITS], 1);
            bkt[p] = xx & RMASK;      // srt: row ids grouped by dest node
        }
    } else {
        // ---- waves 8-15: MFMA gemm1 for this block's 128 rows ----
        int w = (t >> 6) - 8;                        // tile 0..7
        int l = t & 63;
        int R0 = b * BKSZ + w * 16;
        if (R0 < N_NODES) {                          // tiles fully valid or fully skipped
            // stage x tile -> f16 LDS (coalesced): lane covers row l>>2, 32 cols at (l&3)*32
            int row = l >> 2, seg = l & 3;
            const float4* xg = (const float4*)(x + (size_t)(R0 + row) * F_IN) + seg * 8;
            f16* dst = &XH[w][row * WPAD + seg * 32];
#pragma unroll
            for (int j = 0; j < 4; j++) {
                float4 a = xg[2 * j], bb = xg[2 * j + 1];
                f16x8 vv;
                vv[0] = (f16)a.x;  vv[1] = (f16)a.y;  vv[2] = (f16)a.z;  vv[3] = (f16)a.w;
                vv[4] = (f16)bb.x; vv[5] = (f16)bb.y; vv[6] = (f16)bb.z; vv[7] = (f16)bb.w;
                *(f16x8*)(dst + j * 8) = vv;
            }
            // XH[w] is wave-private: ds_write -> ds_read ordered by lgkmcnt, no barrier

            f32x4 acc0 = {0.f, 0.f, 0.f, 0.f};
            f32x4 acc1 = {0.f, 0.f, 0.f, 0.f};
            int lo = l & 15, hi = l >> 4;
            const f16* arow  = &XH[w][lo * WPAD + hi * 8];
            const f16* b0row = &WH[lo * WPAD + hi * 8];
            const f16* b1row = &WH[(16 + lo) * WPAD + hi * 8];
#pragma unroll
            for (int ss = 0; ss < 4; ss++) {         // K-steps of 32
                f16x8 af  = *(const f16x8*)(arow  + ss * 32);
                f16x8 bf0 = *(const f16x8*)(b0row + ss * 32);
                f16x8 bf1 = *(const f16x8*)(b1row + ss * 32);
                acc0 = __builtin_amdgcn_mfma_f32_16x16x32_f16(af, bf0, acc0, 0, 0, 0);
                acc1 = __builtin_amdgcn_mfma_f32_16x16x32_f16(af, bf1, acc1, 0, 0, 0);
            }

            // D: lane holds rows R0 + hi*4 + i, cols lo (acc0) and 16+lo (acc1)
            _Float16* h1h = (_Float16*)h1s;
            int rbase = R0 + hi * 4;
            int lbase_ = w * 16 + hi * 4;            // index into dlds
#pragma unroll
            for (int i = 0; i < 4; i++) {
                float d = dlds[lbase_ + i];
                h1h[(size_t)(rbase + i) * 32 + lo]      = (f16)(d * acc0[i]);
                h1h[(size_t)(rbase + i) * 32 + 16 + lo] = (f16)(d * acc1[i]);
            }
        }
    }
}

// ---------------- conv1 R22: 8 nodes/wave, maskless padded ranges, NT srt loads ----------
// lane = q*8 + o: slot q (0..7) owns node c = waveBase + q; o (0..7) owns feat quad [4o,4o+4).
// Ranges [off,end) are 4-aligned/padded; pad ids = N_NODES (zero row). Gather-bound: FETCH
// 115 MB vs 6.4 MB compulsory = L2 re-fetch of h1s lines evicted by the srt stream.
// R22: srt loads non-temporal so stream-once lines don't age out the 100x-reused table.

__global__ __launch_bounds__(256) void k_conv1(const int* __restrict__ off, const int* __restrict__ end,
                                               const int* __restrict__ srt, const float* __restrict__ dinv,
                                               const unsigned* __restrict__ h1s,
                                               const float* __restrict__ W2, float* __restrict__ h2s4) {
    int t = threadIdx.x;
    if (blockIdx.x == 0 && t < 4) h2s4[(size_t)N_NODES * 4 + t] = 0.0f;  // zero row for k_conv2
    int lane = t & 63, wid = t >> 6;
    int q = lane >> 3, o = lane & 7;
    int c = (blockIdx.x * 4 + wid) * 8 + q;   // grid = N/32 exactly -> c < N_NODES always

    int b = off[c], ep = end[c];              // padded range, b % 4 == 0
    const char* h1b = (const char*)h1s;
    unsigned oo = (unsigned)(o << 3);
    // self-loop row: independent load, issue before the gather loop
    uint2 sv = *(const uint2*)(h1b + (((unsigned)c << 6) + oo));

    float a0a = 0.f, a1a = 0.f, a2a = 0.f, a3a = 0.f;
    float a0b = 0.f, a1b = 0.f, a2b = 0.f, a3b = 0.f;
    float a0c = 0.f, a1c = 0.f, a2c = 0.f, a3c = 0.f;
    float a0d = 0.f, a1d = 0.f, a2d = 0.f, a3d = 0.f;

    int p = b;
    while (__any(p < ep)) {
        int r0 = N_NODES, r1 = N_NODES, r2 = N_NODES, r3 = N_NODES;
        if (p < ep) {                          // exec-masked aligned NT load
            i32x4 rs = __builtin_nontemporal_load((const i32x4*)(srt + p));
            r0 = rs.x; r1 = rs.y; r2 = rs.z; r3 = rs.w;
        }
        uint2 v0 = *(const uint2*)(h1b + (((unsigned)r0 << 6) + oo));
        uint2 v1 = *(const uint2*)(h1b + (((unsigned)r1 << 6) + oo));
        uint2 v2 = *(const uint2*)(h1b + (((unsigned)r2 << 6) + oo));
        uint2 v3 = *(const uint2*)(h1b + (((unsigned)r3 << 6) + oo));
        a0a += __low2float(*(const __half2*)&v0.x);  a1a += __high2float(*(const __half2*)&v0.x);
        a2a += __low2float(*(const __half2*)&v0.y);  a3a += __high2float(*(const __half2*)&v0.y);
        a0b += __low2float(*(const __half2*)&v1.x);  a1b += __high2float(*(const __half2*)&v1.x);
        a2b += __low2float(*(const __half2*)&v1.y);  a3b += __high2float(*(const __half2*)&v1.y);
        a0c += __low2float(*(const __half2*)&v2.x);  a1c += __high2float(*(const __half2*)&v2.x);
        a2c += __low2float(*(const __half2*)&v2.y);  a3c += __high2float(*(const __half2*)&v2.y);
        a0d += __low2float(*(const __half2*)&v3.x);  a1d += __high2float(*(const __half2*)&v3.x);
        a2d += __low2float(*(const __half2*)&v3.y);  a3d += __high2float(*(const __half2*)&v3.y);
        p += 4;
    }

    float di = dinv[c];
    float f0 = (a0a + a0b) + (a0c + a0d) + __low2float(*(const __half2*)&sv.x);
    float f1 = (a1a + a1b) + (a1c + a1d) + __high2float(*(const __half2*)&sv.x);
    float f2 = (a2a + a2b) + (a2c + a2d) + __low2float(*(const __half2*)&sv.y);
    float f3 = (a3a + a3b) + (a3c + a3d) + __high2float(*(const __half2*)&sv.y);

    float h0 = fast_tanh(di * f0);
    float h1 = fast_tanh(di * f1);
    float h2 = fast_tanh(di * f2);
    float h3 = fast_tanh(di * f3);

    // W2 rows for feats 4o..4o+3 (loaded post-loop to keep loop VGPR pressure low)
    const float* Wp = W2 + (o << 2) * 3;
    float p0 = h0 * Wp[0] + h1 * Wp[3] + h2 * Wp[6] + h3 * Wp[9];
    float p1 = h0 * Wp[1] + h1 * Wp[4] + h2 * Wp[7] + h3 * Wp[10];
    float p2 = h0 * Wp[2] + h1 * Wp[5] + h2 * Wp[8] + h3 * Wp[11];
#pragma unroll
    for (int m = 1; m <= 4; m <<= 1) {       // reduce over the 8 feat lanes (o), within each slot
        p0 += __shfl_xor(p0, m);
        p1 += __shfl_xor(p1, m);
        p2 += __shfl_xor(p2, m);
    }
    if (o < 4) {
        float vv = (o == 0) ? p0 : (o == 1) ? p1 : (o == 2) ? p2 : 0.0f;
        h2s4[(size_t)c * 4 + o] = (o < 3) ? di * vv : 0.0f;   // slot 3 = real 0
    }
}

// ---------------- conv2 R22: 4 lanes/node, maskless padded ranges, NT srt loads ----------

__global__ __launch_bounds__(256) void k_conv2(const int* __restrict__ off, const int* __restrict__ end,
                                               const int* __restrict__ srt, const float* __restrict__ dinv,
                                               const float* __restrict__ h2s4, float* __restrict__ out) {
    int gt = blockIdx.x * 256 + threadIdx.x;
    int c = gt >> 2, j = gt & 3;
    if (c >= N_NODES) return;

    const float4* h2v = (const float4*)h2s4;
    int b = off[c], ep = end[c];             // padded, b % 4 == 0
    float4 sv = h2v[c];                      // self-loop term (w component = 0)
    float ax = (j == 0) ? sv.x : 0.0f;
    float ay = (j == 0) ? sv.y : 0.0f;
    float az = (j == 0) ? sv.z : 0.0f;

    for (int p = b + 4 * j; p < ep; p += 16) {
        i32x4 rs = __builtin_nontemporal_load((const i32x4*)(srt + p));
        float4 v0 = h2v[rs.x];
        float4 v1 = h2v[rs.y];
        float4 v2 = h2v[rs.z];
        float4 v3 = h2v[rs.w];
        ax += (v0.x + v1.x) + (v2.x + v3.x);
        ay += (v0.y + v1.y) + (v2.y + v3.y);
        az += (v0.z + v1.z) + (v2.z + v3.z);
    }
#pragma unroll
    for (int m = 1; m <= 2; m <<= 1) {       // reduce over the 4 quad lanes
        ax += __shfl_xor(ax, m);
        ay += __shfl_xor(ay, m);
        az += __shfl_xor(az, m);
    }

    float di = dinv[c];
    if (j < 3) {
        float a = (j == 0) ? ax : (j == 1) ? ay : az;
        out[(size_t)c * 3 + j] = di * a;     // 3 consecutive lanes -> coalesced
    }
}

// ---------------- launch ----------------

extern "C" void kernel_launch(void* const* d_in, const int* in_sizes, int n_in,
                              void* d_out, int out_size, void* d_ws, size_t ws_size,
                              hipStream_t stream) {
    const float* x   = (const float*)d_in[0];
    const int*   ei  = (const int*)d_in[1];  // [2, E] int32
    const float* W1  = (const float*)d_in[2];
    const float* W2  = (const float*)d_in[3];
    float*       out = (float*)d_out;

    const int* row = ei;
    const int* col = ei + N_EDGES;

    char* ws = (char*)d_ws;
    unsigned* bkt = (unsigned*)ws;
    int*      srt = (int*)ws;                 // alias (in-place after k_bucket)
    char*     p   = ws + 4ull * NBKT * CAP;
    int*      gcur = (int*)p;                 p += 4ull * ((NBKT + 63) & ~63);
    int*      off  = (int*)p;                 p += 4ull * N_NODES;
    int*      end  = (int*)p;                 p += 4ull * N_NODES;
    float*    dinv = (float*)p;               p += 4ull * N_NODES;
    unsigned* h1s  = (unsigned*)p;            p += 64ull * (N_NODES + 1);  // +1 zero row
    float*    h2s4 = (float*)p;               // N_NODES+1 rows (zero row for conv2 masks)

    const int B = 256;
    hipMemsetAsync(gcur, 0, 4ull * NBKT, stream);
    hipLaunchKernelGGL(k_part,   dim3(NBLK_E), dim3(512),  0, stream, row, col, gcur, bkt);
    hipLaunchKernelGGL(k_bucket, dim3(NBKT),   dim3(1024), 0, stream,
                       bkt, gcur, off, end, dinv, x, W1, h1s);
    hipLaunchKernelGGL(k_conv1,  dim3(N_NODES / 32), dim3(B), 0, stream,
                       off, end, srt, dinv, h1s, W2, h2s4);
    hipLaunchKernelGGL(k_conv2,  dim3((4 * N_NODES + B - 1) / B), dim3(B), 0, stream,
                       off, end, srt, dinv, h2s4, out);
}

// Round 12
// 210.661 us; speedup vs baseline: 1.0668x; 1.0668x over previous
//
#include <hip/hip_runtime.h>
#include <hip/hip_fp16.h>

#define N_NODES 100000
#define N_EDGES 3200000
#define F_IN    128
#define F_HID   32

#define BSHIFT  7
#define BKSZ    128                               // nodes per bucket
#define NBKT    ((N_NODES + BKSZ - 1) / BKSZ)     // 782
#define CAP     5120                              // bucket capacity: mean 4092 + 8 sigma + 4-align pad
#define CHUNK   4096                              // edges per partition block
#define NBLK_E  ((N_EDGES + CHUNK - 1) / CHUNK)   // 782
#define RBITS   17                                // row id bits (100000 < 2^17)
#define RMASK   0x1FFFF

typedef _Float16 f16;
typedef f16   f16x8 __attribute__((ext_vector_type(8)));
typedef float f32x4 __attribute__((ext_vector_type(4)));
#define WPAD 136   // padded f16 row length: stride 272 B -> 68 dw = 4 mod 32 banks (2-way, free)

// fast tanh: 1 - 2/(exp2(x*2/ln2)+1). v_exp_f32 + v_rcp_f32 are ~1ulp approx
// -> abs err ~1e-6, far under the fp16-storage error budget (absmax ~1e-3).
__device__ __forceinline__ float fast_tanh(float x) {
    float t = __builtin_amdgcn_exp2f(x * 2.88539008f);   // e^{2x}
    return 1.0f - 2.0f * __builtin_amdgcn_rcpf(t + 1.0f);
}

// ---------------- coarse partition (fixed-capacity buckets, relative cursors) ----------------
// gcur[] zeroed by hipMemsetAsync; holds per-bucket edge count after k_part.
// R23: NT hints REVERTED (R22: conv1 41->49 us, FETCH +17 MB — nt demotes the srt stream's
// own short-horizon line reuse; the gather table wasn't being evicted by srt anyway).

__global__ __launch_bounds__(512) void k_part(const int* __restrict__ row, const int* __restrict__ col,
                                              int* __restrict__ gcur, unsigned* __restrict__ bkt) {
    __shared__ int hist[NBKT];
    __shared__ int lbase[NBKT];          // local (block) exclusive prefix
    __shared__ int gbase[NBKT];          // global destination base (absolute)
    __shared__ unsigned perm[CHUNK];     // 16 KB: packed words, bucket-major
    __shared__ unsigned short pb[CHUNK]; // 8 KB: bucket id per slot
    __shared__ int wt[8];
    int t = threadIdx.x;
    for (int i = t; i < NBKT; i += 512) hist[i] = 0;
    __syncthreads();

    int e0 = blockIdx.x * CHUNK;
    int n  = min(CHUNK, N_EDGES - e0);
    int r[8], c[8], rk[8];
#pragma unroll
    for (int k = 0; k < 8; k++) {
        int idx = t + k * 512;
        if (idx < n) {
            r[k]  = row[e0 + idx];
            c[k]  = col[e0 + idx];
            rk[k] = atomicAdd(&hist[c[k] >> BSHIFT], 1);   // local rank in bucket
        }
    }
    __syncthreads();

    // block scan: each thread owns 2 consecutive buckets
    {
        int b0 = t * 2;
        int s0 = (b0     < NBKT) ? hist[b0]     : 0;
        int s1 = (b0 + 1 < NBKT) ? hist[b0 + 1] : 0;
        int tsum = s0 + s1;
        int lane = t & 63, wid = t >> 6;
        int incl = tsum;
#pragma unroll
        for (int sh = 1; sh < 64; sh <<= 1) {
            int u = __shfl_up(incl, sh);
            if (lane >= sh) incl += u;
        }
        if (lane == 63) wt[wid] = incl;
        __syncthreads();
        int wpre = 0;
        for (int w = 0; w < wid; w++) wpre += wt[w];
        int excl = wpre + incl - tsum;
        if (b0     < NBKT) lbase[b0]     = excl;
        if (b0 + 1 < NBKT) lbase[b0 + 1] = excl + s0;
    }
    for (int i = t; i < NBKT; i += 512) {
        int h = hist[i];
        gbase[i] = i * CAP + (h ? atomicAdd(&gcur[i], h) : 0);
    }
    __syncthreads();

#pragma unroll
    for (int k = 0; k < 8; k++) {
        int idx = t + k * 512;
        if (idx < n) {
            int b   = c[k] >> BSHIFT;
            int pos = lbase[b] + rk[k];
            perm[pos] = (unsigned)r[k] | ((unsigned)(c[k] & (BKSZ - 1)) << RBITS);
            pb[pos]   = (unsigned short)b;
        }
    }
    __syncthreads();

    for (int i = t; i < n; i += 512) {
        int b = pb[i];
        bkt[gbase[b] + (i - lbase[b])] = perm[i];
    }
}

// ---------------- k_bucket R21: fine sort + FUSED MFMA gemm1 ----------------
// Phases 1-3 as R17 (stage to LDS, histogram, scan -> off/end(padded)/dinv, dinv also to
// LDS). Then the 16 waves split: waves 0-7 scatter srt (in place), waves 8-15 compute
// h1s = fp16(dinv*(x@W1)) for the block's 128 rows via 8 MFMA 16-row tiles.

__global__ __launch_bounds__(1024) void k_bucket(unsigned* __restrict__ bkt,  // in: bkt, out: srt
                                                 const int* __restrict__ gcur,
                                                 int* __restrict__ off, int* __restrict__ end,
                                                 float* __restrict__ dinv,
                                                 const float* __restrict__ x,
                                                 const float* __restrict__ W1,
                                                 unsigned* __restrict__ h1s) {
    __shared__ unsigned stg[CAP];        // 20.5 KB staging
    __shared__ int cnt[BKSZ];            // histogram; aliased as cur after the scan
    __shared__ int wtot[2];
    __shared__ float dlds[BKSZ];         // dinv for this block's 128 nodes
    __shared__ f16 WH[F_HID * WPAD];     // 8.7 KB: W1 transposed [f][k], f16
    __shared__ f16 XH[8][16 * WPAD];     // 34.8 KB: per-MFMA-wave x tile [row][k], f16
    int t = threadIdx.x, b = blockIdx.x;
    int s = b * CAP, m = gcur[b];        // gcur holds the bucket count
    if (t < BKSZ) cnt[t] = 0;
    for (int i = t; i < F_IN * F_HID; i += 1024) {   // W1[k][f] f32 -> WH[f][k] f16
        int k = i >> 5, f = i & 31;
        WH[f * WPAD + k] = (f16)W1[i];
    }
    if (b == 0 && t < 8)                 // zero row N_NODES for pad-edge gathers
        ((uint2*)h1s)[(size_t)N_NODES * 8 + t] = make_uint2(0u, 0u);
    __syncthreads();
    for (int i = t; i < m; i += 1024) {
        unsigned xx = bkt[s + i];
        stg[i] = xx;
        atomicAdd(&cnt[xx >> RBITS], 1);
    }
    __syncthreads();

    int lane = t & 63, wid = t >> 6;
    int v = 0, v4 = 0, incl = 0;
    if (t < BKSZ) {
        v  = cnt[t];
        v4 = (v + 3) & ~3;            // padded length
        incl = v4;
        #pragma unroll
        for (int sh = 1; sh < 64; sh <<= 1) {
            int u = __shfl_up(incl, sh);
            if (lane >= sh) incl += u;
        }
        if (lane == 63) wtot[wid] = incl;
    }
    __syncthreads();
    if (t < BKSZ) {
        int wpre = (wid == 1) ? wtot[0] : 0;
        int excl = wpre + incl - v4;
        int base = s + excl;          // 4-aligned
        cnt[t] = base;                // cnt reborn as cur (own-slot read above, safe)
        int g = b * BKSZ + t;
        float dv = rsqrtf((float)(v + 1));   // +1 self-loop (real degree)
        dlds[t] = dv;
        if (g < N_NODES) {
            off[g]  = base;
            end[g]  = base + v4;      // PADDED end
            dinv[g] = dv;
        }
        for (int j = v; j < v4; j++) bkt[base + j] = N_NODES;   // pad -> zero row id
    }
    __syncthreads();

    if (t < 512) {
        // ---- waves 0-7: fine-sort scatter (srt) ----
        for (int i = t; i < m; i += 512) {
            unsigned xx = stg[i];
            int p = atomicAdd(&cnt[xx >> RBITS], 1);
            bkt[p] = xx & RMASK;      // srt: row ids grouped by dest node
        }
    } else {
        // ---- waves 8-15: MFMA gemm1 for this block's 128 rows ----
        int w = (t >> 6) - 8;                        // tile 0..7
        int l = t & 63;
        int R0 = b * BKSZ + w * 16;
        if (R0 < N_NODES) {                          // tiles fully valid or fully skipped
            // stage x tile -> f16 LDS (coalesced): lane covers row l>>2, 32 cols at (l&3)*32
            int row = l >> 2, seg = l & 3;
            const float4* xg = (const float4*)(x + (size_t)(R0 + row) * F_IN) + seg * 8;
            f16* dst = &XH[w][row * WPAD + seg * 32];
#pragma unroll
            for (int j = 0; j < 4; j++) {
                float4 a = xg[2 * j], bb = xg[2 * j + 1];
                f16x8 vv;
                vv[0] = (f16)a.x;  vv[1] = (f16)a.y;  vv[2] = (f16)a.z;  vv[3] = (f16)a.w;
                vv[4] = (f16)bb.x; vv[5] = (f16)bb.y; vv[6] = (f16)bb.z; vv[7] = (f16)bb.w;
                *(f16x8*)(dst + j * 8) = vv;
            }
            // XH[w] is wave-private: ds_write -> ds_read ordered by lgkmcnt, no barrier

            f32x4 acc0 = {0.f, 0.f, 0.f, 0.f};
            f32x4 acc1 = {0.f, 0.f, 0.f, 0.f};
            int lo = l & 15, hi = l >> 4;
            const f16* arow  = &XH[w][lo * WPAD + hi * 8];
            const f16* b0row = &WH[lo * WPAD + hi * 8];
            const f16* b1row = &WH[(16 + lo) * WPAD + hi * 8];
#pragma unroll
            for (int ss = 0; ss < 4; ss++) {         // K-steps of 32
                f16x8 af  = *(const f16x8*)(arow  + ss * 32);
                f16x8 bf0 = *(const f16x8*)(b0row + ss * 32);
                f16x8 bf1 = *(const f16x8*)(b1row + ss * 32);
                acc0 = __builtin_amdgcn_mfma_f32_16x16x32_f16(af, bf0, acc0, 0, 0, 0);
                acc1 = __builtin_amdgcn_mfma_f32_16x16x32_f16(af, bf1, acc1, 0, 0, 0);
            }

            // D: lane holds rows R0 + hi*4 + i, cols lo (acc0) and 16+lo (acc1)
            _Float16* h1h = (_Float16*)h1s;
            int rbase = R0 + hi * 4;
            int lbase_ = w * 16 + hi * 4;            // index into dlds
#pragma unroll
            for (int i = 0; i < 4; i++) {
                float d = dlds[lbase_ + i];
                h1h[(size_t)(rbase + i) * 32 + lo]      = (f16)(d * acc0[i]);
                h1h[(size_t)(rbase + i) * 32 + 16 + lo] = (f16)(d * acc1[i]);
            }
        }
    }
}

// ---------------- conv1 R17: 8 nodes/wave, maskless padded ranges, int4 srt loads ----------
// lane = q*8 + o: slot q (0..7) owns node c = waveBase + q; o (0..7) owns feat quad [4o,4o+4).
// Ranges [off,end) are 4-aligned/padded; pad ids = N_NODES (zero row). Structurally
// gather-probe-bound at ~41 us (3.2M random row touches); R17 VALU-trim, R18 split, and
// R22 NT hints all null or negative — this is the floor for this formulation.

__global__ __launch_bounds__(256) void k_conv1(const int* __restrict__ off, const int* __restrict__ end,
                                               const int* __restrict__ srt, const float* __restrict__ dinv,
                                               const unsigned* __restrict__ h1s,
                                               const float* __restrict__ W2, float* __restrict__ h2s4) {
    int t = threadIdx.x;
    if (blockIdx.x == 0 && t < 4) h2s4[(size_t)N_NODES * 4 + t] = 0.0f;  // zero row for k_conv2
    int lane = t & 63, wid = t >> 6;
    int q = lane >> 3, o = lane & 7;
    int c = (blockIdx.x * 4 + wid) * 8 + q;   // grid = N/32 exactly -> c < N_NODES always

    int b = off[c], ep = end[c];              // padded range, b % 4 == 0
    const char* h1b = (const char*)h1s;
    unsigned oo = (unsigned)(o << 3);
    // self-loop row: independent load, issue before the gather loop
    uint2 sv = *(const uint2*)(h1b + (((unsigned)c << 6) + oo));

    float a0a = 0.f, a1a = 0.f, a2a = 0.f, a3a = 0.f;
    float a0b = 0.f, a1b = 0.f, a2b = 0.f, a3b = 0.f;
    float a0c = 0.f, a1c = 0.f, a2c = 0.f, a3c = 0.f;
    float a0d = 0.f, a1d = 0.f, a2d = 0.f, a3d = 0.f;

    int p = b;
    while (__any(p < ep)) {
        int r0 = N_NODES, r1 = N_NODES, r2 = N_NODES, r3 = N_NODES;
        if (p < ep) {                          // exec-masked aligned load; no per-edge selects
            int4 rs = *(const int4*)(srt + p);
            r0 = rs.x; r1 = rs.y; r2 = rs.z; r3 = rs.w;
        }
        uint2 v0 = *(const uint2*)(h1b + (((unsigned)r0 << 6) + oo));
        uint2 v1 = *(const uint2*)(h1b + (((unsigned)r1 << 6) + oo));
        uint2 v2 = *(const uint2*)(h1b + (((unsigned)r2 << 6) + oo));
        uint2 v3 = *(const uint2*)(h1b + (((unsigned)r3 << 6) + oo));
        a0a += __low2float(*(const __half2*)&v0.x);  a1a += __high2float(*(const __half2*)&v0.x);
        a2a += __low2float(*(const __half2*)&v0.y);  a3a += __high2float(*(const __half2*)&v0.y);
        a0b += __low2float(*(const __half2*)&v1.x);  a1b += __high2float(*(const __half2*)&v1.x);
        a2b += __low2float(*(const __half2*)&v1.y);  a3b += __high2float(*(const __half2*)&v1.y);
        a0c += __low2float(*(const __half2*)&v2.x);  a1c += __high2float(*(const __half2*)&v2.x);
        a2c += __low2float(*(const __half2*)&v2.y);  a3c += __high2float(*(const __half2*)&v2.y);
        a0d += __low2float(*(const __half2*)&v3.x);  a1d += __high2float(*(const __half2*)&v3.x);
        a2d += __low2float(*(const __half2*)&v3.y);  a3d += __high2float(*(const __half2*)&v3.y);
        p += 4;
    }

    float di = dinv[c];
    float f0 = (a0a + a0b) + (a0c + a0d) + __low2float(*(const __half2*)&sv.x);
    float f1 = (a1a + a1b) + (a1c + a1d) + __high2float(*(const __half2*)&sv.x);
    float f2 = (a2a + a2b) + (a2c + a2d) + __low2float(*(const __half2*)&sv.y);
    float f3 = (a3a + a3b) + (a3c + a3d) + __high2float(*(const __half2*)&sv.y);

    float h0 = fast_tanh(di * f0);
    float h1 = fast_tanh(di * f1);
    float h2 = fast_tanh(di * f2);
    float h3 = fast_tanh(di * f3);

    // W2 rows for feats 4o..4o+3 (loaded post-loop to keep loop VGPR pressure low)
    const float* Wp = W2 + (o << 2) * 3;
    float p0 = h0 * Wp[0] + h1 * Wp[3] + h2 * Wp[6] + h3 * Wp[9];
    float p1 = h0 * Wp[1] + h1 * Wp[4] + h2 * Wp[7] + h3 * Wp[10];
    float p2 = h0 * Wp[2] + h1 * Wp[5] + h2 * Wp[8] + h3 * Wp[11];
#pragma unroll
    for (int m = 1; m <= 4; m <<= 1) {       // reduce over the 8 feat lanes (o), within each slot
        p0 += __shfl_xor(p0, m);
        p1 += __shfl_xor(p1, m);
        p2 += __shfl_xor(p2, m);
    }
    if (o < 4) {
        float vv = (o == 0) ? p0 : (o == 1) ? p1 : (o == 2) ? p2 : 0.0f;
        h2s4[(size_t)c * 4 + o] = (o < 3) ? di * vv : 0.0f;   // slot 3 = real 0
    }
}

// ---------------- conv2 R17: 4 lanes/node, maskless padded ranges ----------------

__global__ __launch_bounds__(256) void k_conv2(const int* __restrict__ off, const int* __restrict__ end,
                                               const int* __restrict__ srt, const float* __restrict__ dinv,
                                               const float* __restrict__ h2s4, float* __restrict__ out) {
    int gt = blockIdx.x * 256 + threadIdx.x;
    int c = gt >> 2, j = gt & 3;
    if (c >= N_NODES) return;

    const float4* h2v = (const float4*)h2s4;
    int b = off[c], ep = end[c];             // padded, b % 4 == 0
    float4 sv = h2v[c];                      // self-loop term (w component = 0)
    float ax = (j == 0) ? sv.x : 0.0f;
    float ay = (j == 0) ? sv.y : 0.0f;
    float az = (j == 0) ? sv.z : 0.0f;

    for (int p = b + 4 * j; p < ep; p += 16) {
        int4 rs = *(const int4*)(srt + p);
        float4 v0 = h2v[rs.x];
        float4 v1 = h2v[rs.y];
        float4 v2 = h2v[rs.z];
        float4 v3 = h2v[rs.w];
        ax += (v0.x + v1.x) + (v2.x + v3.x);
        ay += (v0.y + v1.y) + (v2.y + v3.y);
        az += (v0.z + v1.z) + (v2.z + v3.z);
    }
#pragma unroll
    for (int m = 1; m <= 2; m <<= 1) {       // reduce over the 4 quad lanes
        ax += __shfl_xor(ax, m);
        ay += __shfl_xor(ay, m);
        az += __shfl_xor(az, m);
    }

    float di = dinv[c];
    if (j < 3) {
        float a = (j == 0) ? ax : (j == 1) ? ay : az;
        out[(size_t)c * 3 + j] = di * a;     // 3 consecutive lanes -> coalesced
    }
}

// ---------------- launch ----------------

extern "C" void kernel_launch(void* const* d_in, const int* in_sizes, int n_in,
                              void* d_out, int out_size, void* d_ws, size_t ws_size,
                              hipStream_t stream) {
    const float* x   = (const float*)d_in[0];
    const int*   ei  = (const int*)d_in[1];  // [2, E] int32
    const float* W1  = (const float*)d_in[2];
    const float* W2  = (const float*)d_in[3];
    float*       out = (float*)d_out;

    const int* row = ei;
    const int* col = ei + N_EDGES;

    char* ws = (char*)d_ws;
    unsigned* bkt = (unsigned*)ws;
    int*      srt = (int*)ws;                 // alias (in-place after k_bucket)
    char*     p   = ws + 4ull * NBKT * CAP;
    int*      gcur = (int*)p;                 p += 4ull * ((NBKT + 63) & ~63);
    int*      off  = (int*)p;                 p += 4ull * N_NODES;
    int*      end  = (int*)p;                 p += 4ull * N_NODES;
    float*    dinv = (float*)p;               p += 4ull * N_NODES;
    unsigned* h1s  = (unsigned*)p;            p += 64ull * (N_NODES + 1);  // +1 zero row
    float*    h2s4 = (float*)p;               // N_NODES+1 rows (zero row for conv2 masks)

    const int B = 256;
    hipMemsetAsync(gcur, 0, 4ull * NBKT, stream);
    hipLaunchKernelGGL(k_part,   dim3(NBLK_E), dim3(512),  0, stream, row, col, gcur, bkt);
    hipLaunchKernelGGL(k_bucket, dim3(NBKT),   dim3(1024), 0, stream,
                       bkt, gcur, off, end, dinv, x, W1, h1s);
    hipLaunchKernelGGL(k_conv1,  dim3(N_NODES / 32), dim3(B), 0, stream,
                       off, end, srt, dinv, h1s, W2, h2s4);
    hipLaunchKernelGGL(k_conv2,  dim3((4 * N_NODES + B - 1) / B), dim3(B), 0, stream,
                       off, end, srt, dinv, h2s4, out);
}